// Round 1
// baseline (1168.100 us; speedup 1.0000x reference)
//
#include <hip/hip_runtime.h>
#include <math.h>

#define N_NODES 20000
#define N_EDGES 160000
#define N_CFG   1000
#define OP_FEAT 140
#define CFG_FEAT 24
#define HID     256
#define EMB     128
#define EARLY_IN 268   // EMB + OP_FEAT
#define LATE_IN  280   // CFG_FEAT + HID
#define E_TOT   (N_EDGES + N_NODES)

__device__ __forceinline__ float gelu_f(float x) {
  return 0.5f * x * (1.0f + erff(x * 0.70710678118654752f));
}

// ---------------------------------------------------------------- prep
// x268[row] = [ renorm(embed[opcode[row]]) (128) | (feat-mean)/(std+1e-4) (140) ]
__global__ __launch_bounds__(256) void prep_kernel(
    const float* __restrict__ node_feat, const float* __restrict__ nf_mean,
    const float* __restrict__ nf_std, const float* __restrict__ emb_table,
    const int* __restrict__ opcode, float* __restrict__ x268)
{
  int wave = threadIdx.x >> 6;
  int lane = threadIdx.x & 63;
  int row = blockIdx.x * 4 + wave;
  if (row >= N_NODES) return;
  int op = opcode[row];
  float t0 = emb_table[op * EMB + lane];
  float t1 = emb_table[op * EMB + 64 + lane];
  float ss = t0 * t0 + t1 * t1;
  #pragma unroll
  for (int off = 32; off; off >>= 1) ss += __shfl_xor(ss, off);
  float nrm = sqrtf(ss);
  float sc = fminf(1.0f, 1.0f / (nrm + 1e-7f));
  float* dst = x268 + (size_t)row * EARLY_IN;
  dst[lane] = t0 * sc;
  dst[64 + lane] = t1 * sc;
  for (int k = lane; k < OP_FEAT; k += 64)
    dst[EMB + k] = (node_feat[(size_t)row * OP_FEAT + k] - nf_mean[k]) / (nf_std[k] + 1e-4f);
}

// ---------------------------------------------------------------- f32 GEMM
// C[M,N] = A[M,K] @ B[K,N] (+ bias). BM=BN=64, BK=16, 256 thr, 4x4/thr.
__global__ __launch_bounds__(256) void gemm_f32(
    const float* __restrict__ A, const float* __restrict__ B,
    const float* __restrict__ bias, float* __restrict__ C,
    int M, int N, int K)
{
  __shared__ float As[16][65];
  __shared__ float Bs[16][65];
  int tid = threadIdx.x;
  int bm = blockIdx.x * 64, bn = blockIdx.y * 64;
  int tx = tid & 15, ty = tid >> 4;
  float acc[4][4] = {};
  for (int k0 = 0; k0 < K; k0 += 16) {
    // A tile: 64 rows x 16 k
    {
      int row = tid >> 2;
      int kk = (tid & 3) * 4;
      int gr = bm + row;
      float4 a = {0, 0, 0, 0};
      if (gr < M) {
        if (k0 + kk + 3 < K) {
          a = *(const float4*)(A + (size_t)gr * K + k0 + kk);
        } else {
          float tmp[4] = {0, 0, 0, 0};
          for (int i = 0; i < 4; i++)
            if (k0 + kk + i < K) tmp[i] = A[(size_t)gr * K + k0 + kk + i];
          a = make_float4(tmp[0], tmp[1], tmp[2], tmp[3]);
        }
      }
      As[kk + 0][row] = a.x; As[kk + 1][row] = a.y;
      As[kk + 2][row] = a.z; As[kk + 3][row] = a.w;
    }
    // B tile: 16 k x 64 n   (N is a multiple of 64)
    {
      int kr = tid >> 4;
      int nc = (tid & 15) * 4;
      float4 b = {0, 0, 0, 0};
      if (k0 + kr < K) b = *(const float4*)(B + (size_t)(k0 + kr) * N + bn + nc);
      Bs[kr][nc + 0] = b.x; Bs[kr][nc + 1] = b.y;
      Bs[kr][nc + 2] = b.z; Bs[kr][nc + 3] = b.w;
    }
    __syncthreads();
    #pragma unroll
    for (int k = 0; k < 16; k++) {
      float av[4], bv[4];
      #pragma unroll
      for (int i = 0; i < 4; i++) av[i] = As[k][ty * 4 + i];
      #pragma unroll
      for (int j = 0; j < 4; j++) bv[j] = Bs[k][tx * 4 + j];
      #pragma unroll
      for (int i = 0; i < 4; i++)
        #pragma unroll
        for (int j = 0; j < 4; j++) acc[i][j] += av[i] * bv[j];
    }
    __syncthreads();
  }
  #pragma unroll
  for (int i = 0; i < 4; i++) {
    int gr = bm + ty * 4 + i;
    if (gr >= M) continue;
    #pragma unroll
    for (int j = 0; j < 4; j++) {
      int gc = bn + tx * 4 + j;
      float v = acc[i][j];
      if (bias) v += bias[gc];
      C[(size_t)gr * N + gc] = v;
    }
  }
}

// ---------------------------------------------------------------- column stats
__global__ void colstats(const float* __restrict__ X, int M, int C,
                         float* __restrict__ stats)
{
  int c = threadIdx.x;
  if (c >= C) return;
  int r0 = blockIdx.x * 64;
  int r1 = min(r0 + 64, M);
  float s = 0.f, sq = 0.f;
  for (int r = r0; r < r1; r++) {
    float v = X[(size_t)r * C + c];
    s += v; sq += v * v;
  }
  atomicAdd(&stats[c], s);
  atomicAdd(&stats[C + c], sq);
}

__global__ void norm_gelu(const float* __restrict__ X, float* __restrict__ Y,
                          int M, int C, const float* __restrict__ stats)
{
  int i = blockIdx.x * blockDim.x + threadIdx.x;
  if (i >= M * C) return;
  int c = i % C;
  float invM = 1.0f / (float)M;
  float mean = stats[c] * invM;
  float var = stats[C + c] * invM - mean * mean;
  float inv = rsqrtf(var + 1e-5f);
  float y = (X[i] - mean) * inv;
  Y[i] = gelu_f(y);
}

// ---------------------------------------------------------------- CSR build
__global__ void edge_count(const int* __restrict__ ei, int* __restrict__ counts) {
  int e = blockIdx.x * blockDim.x + threadIdx.x;
  if (e >= E_TOT) return;
  int dst = (e < N_EDGES) ? ei[N_EDGES + e] : (e - N_EDGES);
  atomicAdd(&counts[dst], 1);
}

__global__ __launch_bounds__(1024) void scan_kernel(const int* __restrict__ counts,
                                                    int* __restrict__ indptr)
{
  __shared__ int sh[1024];
  int t = threadIdx.x;
  const int chunk = (N_NODES + 1023) / 1024;
  int start = t * chunk, end = min(start + chunk, N_NODES);
  int sum = 0;
  for (int i = start; i < end; i++) sum += counts[i];
  sh[t] = sum;
  __syncthreads();
  for (int off = 1; off < 1024; off <<= 1) {
    int v = (t >= off) ? sh[t - off] : 0;
    __syncthreads();
    sh[t] += v;
    __syncthreads();
  }
  int run = (t > 0) ? sh[t - 1] : 0;
  for (int i = start; i < end; i++) { indptr[i] = run; run += counts[i]; }
  if (t == 1023) indptr[N_NODES] = run;
}

__global__ void edge_fill(const int* __restrict__ ei, const int* __restrict__ indptr,
                          int* __restrict__ cursor, int* __restrict__ col)
{
  int e = blockIdx.x * blockDim.x + threadIdx.x;
  if (e >= E_TOT) return;
  int src, dst;
  if (e < N_EDGES) { src = ei[e]; dst = ei[N_EDGES + e]; }
  else             { src = dst = e - N_EDGES; }
  int pos = indptr[dst] + atomicAdd(&cursor[dst], 1);
  col[pos] = src;
}

// ---------------------------------------------------------------- GAT aggregation
// One wave per destination node; online softmax over incoming edges.
__global__ __launch_bounds__(256) void gat_agg(
    const float* __restrict__ xl, const float* __restrict__ xr,
    const int* __restrict__ indptr, const int* __restrict__ col,
    const float* __restrict__ att, const float* __restrict__ bias,
    float* __restrict__ out)
{
  int wave = threadIdx.x >> 6, lane = threadIdx.x & 63;
  int node = blockIdx.x * 4 + wave;
  if (node >= N_NODES) return;
  float attc[4], xri[4], o[4] = {0, 0, 0, 0};
  #pragma unroll
  for (int k = 0; k < 4; k++) {
    attc[k] = att[lane + 64 * k];
    xri[k] = xr[(size_t)node * HID + lane + 64 * k];
  }
  float m = -INFINITY, s = 0.f;
  int e0 = indptr[node], e1 = indptr[node + 1];
  for (int e = e0; e < e1; e++) {
    int j = col[e];
    float xlj[4], p = 0.f;
    #pragma unroll
    for (int k = 0; k < 4; k++) {
      xlj[k] = xl[(size_t)j * HID + lane + 64 * k];
      float h = xlj[k] + xri[k];
      float lr = h > 0.f ? h : 0.2f * h;
      p += lr * attc[k];
    }
    #pragma unroll
    for (int off = 32; off; off >>= 1) p += __shfl_xor(p, off);
    float mn = fmaxf(m, p);
    float scale = __expf(m - mn);
    float w = __expf(p - mn);
    s = s * scale + w;
    #pragma unroll
    for (int k = 0; k < 4; k++) o[k] = o[k] * scale + w * xlj[k];
    m = mn;
  }
  float inv = 1.0f / (s + 1e-16f);
  #pragma unroll
  for (int k = 0; k < 4; k++)
    out[(size_t)node * HID + lane + 64 * k] = o[k] * inv + bias[lane + 64 * k];
}

// ---------------------------------------------------------------- pooling
__device__ __forceinline__ unsigned fenc(float f) {
  unsigned b = __float_as_uint(f);
  return (b & 0x80000000u) ? ~b : (b | 0x80000000u);
}
__device__ __forceinline__ float fdec(unsigned u) {
  unsigned b = (u & 0x80000000u) ? (u & 0x7FFFFFFFu) : ~u;
  return __uint_as_float(b);
}

__global__ void pool_reduce(const float* __restrict__ X, float* __restrict__ psum,
                            unsigned* __restrict__ pmax)
{
  int c = threadIdx.x;
  int r0 = blockIdx.x * 64, r1 = min(r0 + 64, N_NODES);
  float s = 0.f, mx = -INFINITY;
  for (int r = r0; r < r1; r++) {
    float v = X[(size_t)r * HID + c];
    s += v; mx = fmaxf(mx, v);
  }
  atomicAdd(&psum[c], s);
  atomicMax(&pmax[c], fenc(mx));
}

__global__ void pool_finalize(const float* __restrict__ psum,
                              const unsigned* __restrict__ pmax,
                              float* __restrict__ pool)
{
  int c = threadIdx.x;
  pool[c] = psum[c] * (1.0f / N_NODES) + fdec(pmax[c]);
}

// ---------------------------------------------------------------- late stage
__global__ void build_xlate(const float* __restrict__ cfg, const float* __restrict__ cmean,
                            const float* __restrict__ cstd, const float* __restrict__ pool,
                            float* __restrict__ xlate)
{
  int i = blockIdx.x * blockDim.x + threadIdx.x;
  if (i >= N_CFG * LATE_IN) return;
  int r = i / LATE_IN, c = i % LATE_IN;
  float v;
  if (c < CFG_FEAT) v = (cfg[r * CFG_FEAT + c] - cmean[c]) / (cstd[c] + 1e-4f);
  else v = pool[c - CFG_FEAT];
  xlate[i] = v;
}

__global__ __launch_bounds__(64) void pred_kernel(
    const float* __restrict__ h2, const float* __restrict__ W,
    const float* __restrict__ b, float* __restrict__ out)
{
  int r = blockIdx.x, lane = threadIdx.x;
  float v = h2[(size_t)r * 128 + lane] * W[lane] +
            h2[(size_t)r * 128 + 64 + lane] * W[64 + lane];
  #pragma unroll
  for (int off = 32; off; off >>= 1) v += __shfl_xor(v, off);
  if (lane == 0) out[r] = v + b[0];
}

// ================================================================ launch
extern "C" void kernel_launch(void* const* d_in, const int* in_sizes, int n_in,
                              void* d_out, int out_size, void* d_ws, size_t ws_size,
                              hipStream_t stream)
{
  const float* node_feat  = (const float*)d_in[0];
  const float* config_feat = (const float*)d_in[1];
  const float* nf_mean    = (const float*)d_in[2];
  const float* nf_std     = (const float*)d_in[3];
  const float* cf_mean    = (const float*)d_in[4];
  const float* cf_std     = (const float*)d_in[5];
  const float* emb_table  = (const float*)d_in[6];
  const float* early_W1   = (const float*)d_in[7];
  const float* early_W2   = (const float*)d_in[8];
  const float* gat_Wl     = (const float*)d_in[9];
  const float* gat_bl     = (const float*)d_in[10];
  const float* gat_Wr     = (const float*)d_in[11];
  const float* gat_br     = (const float*)d_in[12];
  const float* gat_att    = (const float*)d_in[13];
  const float* gat_bias   = (const float*)d_in[14];
  const float* late_W1    = (const float*)d_in[15];
  const float* late_W2    = (const float*)d_in[16];
  const float* pred_W     = (const float*)d_in[17];
  const float* pred_b     = (const float*)d_in[18];
  const int*   node_opcode = (const int*)d_in[19];
  const int*   edge_index  = (const int*)d_in[20];
  float* out = (float*)d_out;
  (void)in_sizes; (void)n_in; (void)out_size; (void)ws_size;

  char* ws = (char*)d_ws;
  size_t off = 0;
  auto alloc = [&](size_t bytes) -> void* {
    void* p = ws + off;
    off += (bytes + 255) & ~255ull;
    return p;
  };
  float* x268  = (float*)alloc((size_t)N_NODES * EARLY_IN * 4);
  float* bufA  = (float*)alloc((size_t)N_NODES * HID * 4);
  float* bufB  = (float*)alloc((size_t)N_NODES * HID * 4);
  float* xl    = (float*)alloc((size_t)N_NODES * HID * 4);
  float* xr    = (float*)alloc((size_t)N_NODES * HID * 4);
  float* stats = (float*)alloc(2 * HID * 4);
  int* counts  = (int*)alloc(N_NODES * 4);
  int* indptr  = (int*)alloc((N_NODES + 1) * 4);
  int* colidx  = (int*)alloc((size_t)E_TOT * 4);
  float* psum  = (float*)alloc(HID * 4);
  unsigned* pmax = (unsigned*)alloc(HID * 4);
  float* pool  = (float*)alloc(HID * 4);
  float* xlate = (float*)alloc((size_t)N_CFG * LATE_IN * 4);
  float* h1    = (float*)alloc((size_t)N_CFG * HID * 4);
  float* h2    = (float*)alloc((size_t)N_CFG * 128 * 4);

  auto run_gemm = [&](const float* A, const float* B, const float* bias, float* C,
                      int M, int N, int K) {
    dim3 grid((M + 63) / 64, N / 64);
    hipLaunchKernelGGL(gemm_f32, grid, dim3(256), 0, stream, A, B, bias, C, M, N, K);
  };
  auto run_norm = [&](const float* X, float* Y, int M, int C) {
    hipMemsetAsync(stats, 0, 2 * C * sizeof(float), stream);
    hipLaunchKernelGGL(colstats, dim3((M + 63) / 64), dim3(C), 0, stream, X, M, C, stats);
    hipLaunchKernelGGL(norm_gelu, dim3((M * C + 255) / 256), dim3(256), 0, stream,
                       X, Y, M, C, stats);
  };

  // prep + early MLP
  hipLaunchKernelGGL(prep_kernel, dim3((N_NODES + 3) / 4), dim3(256), 0, stream,
                     node_feat, nf_mean, nf_std, emb_table, node_opcode, x268);
  run_gemm(x268, early_W1, nullptr, bufB, N_NODES, HID, EARLY_IN);
  run_norm(bufB, bufA, N_NODES, HID);
  run_gemm(bufA, early_W2, nullptr, bufB, N_NODES, HID, HID);
  run_norm(bufB, bufA, N_NODES, HID);

  // CSR build (dst-sorted incoming edge lists, incl. self-loops)
  hipMemsetAsync(counts, 0, N_NODES * 4, stream);
  hipLaunchKernelGGL(edge_count, dim3((E_TOT + 255) / 256), dim3(256), 0, stream,
                     edge_index, counts);
  hipLaunchKernelGGL(scan_kernel, dim3(1), dim3(1024), 0, stream, counts, indptr);
  hipMemsetAsync(counts, 0, N_NODES * 4, stream);
  hipLaunchKernelGGL(edge_fill, dim3((E_TOT + 255) / 256), dim3(256), 0, stream,
                     edge_index, indptr, counts, colidx);

  // 4 GAT layers
  for (int l = 0; l < 4; l++) {
    run_gemm(bufA, gat_Wl + (size_t)l * HID * HID, gat_bl + l * HID, xl, N_NODES, HID, HID);
    run_gemm(bufA, gat_Wr + (size_t)l * HID * HID, gat_br + l * HID, xr, N_NODES, HID, HID);
    hipLaunchKernelGGL(gat_agg, dim3((N_NODES + 3) / 4), dim3(256), 0, stream,
                       xl, xr, indptr, colidx, gat_att + l * HID, gat_bias + l * HID, bufB);
    run_norm(bufB, bufA, N_NODES, HID);
  }

  // pooling
  hipMemsetAsync(psum, 0, HID * 4, stream);
  hipMemsetAsync(pmax, 0, HID * 4, stream);
  hipLaunchKernelGGL(pool_reduce, dim3((N_NODES + 63) / 64), dim3(HID), 0, stream,
                     bufA, psum, pmax);
  hipLaunchKernelGGL(pool_finalize, dim3(1), dim3(HID), 0, stream, psum, pmax, pool);

  // late MLP
  hipLaunchKernelGGL(build_xlate, dim3((N_CFG * LATE_IN + 255) / 256), dim3(256), 0, stream,
                     config_feat, cf_mean, cf_std, pool, xlate);
  run_gemm(xlate, late_W1, nullptr, h1, N_CFG, HID, LATE_IN);
  run_norm(h1, h1, N_CFG, HID);
  run_gemm(h1, late_W2, nullptr, h2, N_CFG, 128, HID);
  run_norm(h2, h2, N_CFG, 128);
  hipLaunchKernelGGL(pred_kernel, dim3(N_CFG), dim3(64), 0, stream, h2, pred_W, pred_b, out);
}

// Round 3
// 674.562 us; speedup vs baseline: 1.7316x; 1.7316x over previous
//
#include <hip/hip_runtime.h>
#include <math.h>

#define N_NODES 20000
#define N_EDGES 160000
#define N_CFG   1000
#define OP_FEAT 140
#define CFG_FEAT 24
#define HID     256
#define EMB     128
#define E_TOT   (N_EDGES + N_NODES)
#define K288    288          // 268 and 280 padded to multiple of 32
#define MPAD    20096        // 157 * 128
#define NW      512          // fused Wl|Wr output width

typedef __attribute__((ext_vector_type(8))) short short8v;
typedef __attribute__((ext_vector_type(4))) float f32x4;

__device__ __forceinline__ short f2bf(float f) {
  unsigned u = __float_as_uint(f);
  unsigned r = (u + 0x7FFFu + ((u >> 16) & 1u)) >> 16;
  return (short)r;
}
__device__ __forceinline__ float bf2f(short s) {
  return __uint_as_float(((unsigned)(unsigned short)s) << 16);
}
__device__ __forceinline__ float gelu_f(float x) {
  return 0.5f * x * (1.0f + erff(x * 0.70710678118654752f));
}

#define GLOAD_LDS(gptr, lptr) __builtin_amdgcn_global_load_lds( \
    (const __attribute__((address_space(1))) void*)(gptr),      \
    (__attribute__((address_space(3))) void*)(lptr), 16, 0, 0)

// ---------------------------------------------------------------- weight prep
// W [K][N] f32 -> Wt [N][Kpad] bf16 (zero-pad k >= K)
__global__ void convert_wt(const float* __restrict__ W, short* __restrict__ Wt,
                           int K, int N, int Kpad)
{
  int i = blockIdx.x * blockDim.x + threadIdx.x;
  if (i >= N * Kpad) return;
  int n = i / Kpad, k = i % Kpad;
  Wt[i] = (k < K) ? f2bf(W[(size_t)k * N + n]) : (short)0;
}

// gat Wl|Wr fused transpose: dst[l][n(512)][k(256)]
__global__ void gat_wt_prep(const float* __restrict__ Wl, const float* __restrict__ Wr,
                            short* __restrict__ dst)
{
  int i = blockIdx.x * blockDim.x + threadIdx.x;
  if (i >= 4 * NW * HID) return;
  int l = i >> 17, rem = i & 131071;
  int n = rem >> 8, k = rem & 255;
  float v = (n < HID) ? Wl[(size_t)l * HID * HID + (size_t)k * HID + n]
                      : Wr[(size_t)l * HID * HID + (size_t)k * HID + (n - HID)];
  dst[i] = f2bf(v);
}

__global__ void bias_cat(const float* __restrict__ bl, const float* __restrict__ br,
                         float* __restrict__ blr)
{
  int i = blockIdx.x * blockDim.x + threadIdx.x;
  if (i >= 4 * NW) return;
  int l = i >> 9, j = i & 511;
  blr[i] = (j < HID) ? bl[l * HID + j] : br[l * HID + j - HID];
}

// ---------------------------------------------------------------- prep
__global__ __launch_bounds__(256) void prep_kernel(
    const float* __restrict__ node_feat, const float* __restrict__ nf_mean,
    const float* __restrict__ nf_std, const float* __restrict__ emb_table,
    const int* __restrict__ opcode, short* __restrict__ x268b)
{
  int wave = threadIdx.x >> 6;
  int lane = threadIdx.x & 63;
  int row = blockIdx.x * 4 + wave;
  if (row >= N_NODES) return;
  int op = opcode[row];
  float t0 = emb_table[op * EMB + lane];
  float t1 = emb_table[op * EMB + 64 + lane];
  float ss = t0 * t0 + t1 * t1;
  #pragma unroll
  for (int off = 32; off; off >>= 1) ss += __shfl_xor(ss, off);
  float sc = fminf(1.0f, 1.0f / (sqrtf(ss) + 1e-7f));
  short* dst = x268b + (size_t)row * K288;
  dst[lane] = f2bf(t0 * sc);
  dst[64 + lane] = f2bf(t1 * sc);
  for (int k = lane; k < OP_FEAT; k += 64)
    dst[EMB + k] = f2bf((node_feat[(size_t)row * OP_FEAT + k] - nf_mean[k]) / (nf_std[k] + 1e-4f));
  if (lane < K288 - EMB - OP_FEAT) dst[EMB + OP_FEAT + lane] = 0;
}

// ---------------------------------------------------------------- MFMA GEMM
// C[M,N] = A[M,Kpad]_bf16 @ Wt[N,Kpad]_bf16^T (+bias). 128x128 tile, BK=32.
__global__ __launch_bounds__(256) void gemm_mfma(
    const short* __restrict__ A, const short* __restrict__ Wt,
    const float* __restrict__ bias, float* __restrict__ C,
    int M, int N, int Kpad)
{
  __shared__ __align__(16) short As[4][128][8];
  __shared__ __align__(16) short Bs[4][128][8];
  int tid = threadIdx.x;
  int wave = tid >> 6, lane = tid & 63;
  int bm = blockIdx.x * 128, bn = blockIdx.y * 128;
  int wr = (wave >> 1) * 64, wc = (wave & 1) * 64;
  int g = lane >> 4, r16 = lane & 15;
  f32x4 acc[4][4] = {};

  for (int k0 = 0; k0 < Kpad; k0 += 32) {
    #pragma unroll
    for (int s2 = 0; s2 < 2; s2++) {
      int s = wave * 2 + s2;
      int sg = s >> 1, r0 = (s & 1) * 64;
      GLOAD_LDS(A  + (size_t)(bm + r0 + lane) * Kpad + k0 + sg * 8, &As[sg][r0][0]);
      GLOAD_LDS(Wt + (size_t)(bn + r0 + lane) * Kpad + k0 + sg * 8, &Bs[sg][r0][0]);
    }
    __syncthreads();
    short8v af[4], bfv[4];
    #pragma unroll
    for (int mi = 0; mi < 4; mi++)
      af[mi] = *(const short8v*)&As[g][wr + mi * 16 + r16][0];
    #pragma unroll
    for (int ni = 0; ni < 4; ni++)
      bfv[ni] = *(const short8v*)&Bs[g][wc + ni * 16 + r16][0];
    #pragma unroll
    for (int mi = 0; mi < 4; mi++)
      #pragma unroll
      for (int ni = 0; ni < 4; ni++)
        acc[mi][ni] = __builtin_amdgcn_mfma_f32_16x16x32_bf16(af[mi], bfv[ni], acc[mi][ni], 0, 0, 0);
    __syncthreads();
  }

  int rg = lane >> 4;
  #pragma unroll
  for (int mi = 0; mi < 4; mi++) {
    #pragma unroll
    for (int r = 0; r < 4; r++) {
      int gr = bm + wr + mi * 16 + rg * 4 + r;
      if (gr >= M) continue;
      #pragma unroll
      for (int ni = 0; ni < 4; ni++) {
        int gc = bn + wc + ni * 16 + r16;
        float v = acc[mi][ni][r];
        if (bias) v += bias[gc];
        C[(size_t)gr * N + gc] = v;
      }
    }
  }
}

// ---------------------------------------------------------------- column stats
__global__ void colstats(const float* __restrict__ X, int M, int C,
                         float* __restrict__ stats)
{
  int c = threadIdx.x;
  int r0 = blockIdx.x * 64;
  int r1 = min(r0 + 64, M);
  float s = 0.f, sq = 0.f;
  for (int r = r0; r < r1; r++) {
    float v = X[(size_t)r * C + c];
    s += v; sq += v * v;
  }
  atomicAdd(&stats[c], s);
  atomicAdd(&stats[C + c], sq);
}

// norm over rows + exact gelu; optional f32 and bf16 outputs
__global__ void norm_gelu(const float* __restrict__ X, float* __restrict__ Yf,
                          short* __restrict__ Yb, int M, int C,
                          const float* __restrict__ stats)
{
  int i = blockIdx.x * blockDim.x + threadIdx.x;
  if (i >= M * C) return;
  int c = i % C;
  float invM = 1.0f / (float)M;
  float mean = stats[c] * invM;
  float var = stats[C + c] * invM - mean * mean;
  float y = gelu_f((X[i] - mean) * rsqrtf(var + 1e-5f));
  if (Yf) Yf[i] = y;
  if (Yb) Yb[i] = f2bf(y);
}

// ---------------------------------------------------------------- CSR build
__global__ void edge_count(const int* __restrict__ ei, int* __restrict__ counts) {
  int e = blockIdx.x * blockDim.x + threadIdx.x;
  if (e >= E_TOT) return;
  int dst = (e < N_EDGES) ? ei[N_EDGES + e] : (e - N_EDGES);
  atomicAdd(&counts[dst], 1);
}

__global__ __launch_bounds__(1024) void scan_kernel(const int* __restrict__ counts,
                                                    int* __restrict__ indptr)
{
  __shared__ int sh[1024];
  int t = threadIdx.x;
  const int chunk = (N_NODES + 1023) / 1024;
  int start = t * chunk, end = min(start + chunk, N_NODES);
  int sum = 0;
  for (int i = start; i < end; i++) sum += counts[i];
  sh[t] = sum;
  __syncthreads();
  for (int off = 1; off < 1024; off <<= 1) {
    int v = (t >= off) ? sh[t - off] : 0;
    __syncthreads();
    sh[t] += v;
    __syncthreads();
  }
  int run = (t > 0) ? sh[t - 1] : 0;
  for (int i = start; i < end; i++) { indptr[i] = run; run += counts[i]; }
  if (t == 1023) indptr[N_NODES] = run;
}

__global__ void edge_fill(const int* __restrict__ ei, const int* __restrict__ indptr,
                          int* __restrict__ cursor, int* __restrict__ col)
{
  int e = blockIdx.x * blockDim.x + threadIdx.x;
  if (e >= E_TOT) return;
  int src, dst;
  if (e < N_EDGES) { src = ei[e]; dst = ei[N_EDGES + e]; }
  else             { src = dst = e - N_EDGES; }
  int pos = indptr[dst] + atomicAdd(&cursor[dst], 1);
  col[pos] = src;
}

// ---------------------------------------------------------------- GAT aggregation
// xlr [N, 512] = [xl | xr]. One wave per destination node; online softmax.
__global__ __launch_bounds__(256) void gat_agg(
    const float* __restrict__ xlr,
    const int* __restrict__ indptr, const int* __restrict__ col,
    const float* __restrict__ att, const float* __restrict__ bias,
    float* __restrict__ out)
{
  int wave = threadIdx.x >> 6, lane = threadIdx.x & 63;
  int node = blockIdx.x * 4 + wave;
  if (node >= N_NODES) return;
  float attc[4], xri[4], o[4] = {0, 0, 0, 0};
  #pragma unroll
  for (int k = 0; k < 4; k++) {
    attc[k] = att[lane + 64 * k];
    xri[k] = xlr[(size_t)node * NW + HID + lane + 64 * k];
  }
  float m = -INFINITY, s = 0.f;
  int e0 = indptr[node], e1 = indptr[node + 1];
  for (int e = e0; e < e1; e++) {
    int j = col[e];
    float xlj[4], p = 0.f;
    #pragma unroll
    for (int k = 0; k < 4; k++) {
      xlj[k] = xlr[(size_t)j * NW + lane + 64 * k];
      float h = xlj[k] + xri[k];
      float lr = h > 0.f ? h : 0.2f * h;
      p += lr * attc[k];
    }
    #pragma unroll
    for (int off = 32; off; off >>= 1) p += __shfl_xor(p, off);
    float mn = fmaxf(m, p);
    float scale = __expf(m - mn);
    float w = __expf(p - mn);
    s = s * scale + w;
    #pragma unroll
    for (int k = 0; k < 4; k++) o[k] = o[k] * scale + w * xlj[k];
    m = mn;
  }
  float inv = 1.0f / (s + 1e-16f);
  #pragma unroll
  for (int k = 0; k < 4; k++)
    out[(size_t)node * HID + lane + 64 * k] = o[k] * inv + bias[lane + 64 * k];
}

// ---------------------------------------------------------------- pooling
__device__ __forceinline__ unsigned fenc(float f) {
  unsigned b = __float_as_uint(f);
  return (b & 0x80000000u) ? ~b : (b | 0x80000000u);
}
__device__ __forceinline__ float fdec(unsigned u) {
  unsigned b = (u & 0x80000000u) ? (u & 0x7FFFFFFFu) : ~u;
  return __uint_as_float(b);
}

__global__ void pool_reduce(const short* __restrict__ Xb, float* __restrict__ psum,
                            unsigned* __restrict__ pmax)
{
  int c = threadIdx.x;
  int r0 = blockIdx.x * 64, r1 = min(r0 + 64, N_NODES);
  float s = 0.f, mx = -INFINITY;
  for (int r = r0; r < r1; r++) {
    float v = bf2f(Xb[(size_t)r * HID + c]);
    s += v; mx = fmaxf(mx, v);
  }
  atomicAdd(&psum[c], s);
  atomicMax(&pmax[c], fenc(mx));
}

__global__ void pool_finalize(const float* __restrict__ psum,
                              const unsigned* __restrict__ pmax,
                              float* __restrict__ pool)
{
  int c = threadIdx.x;
  pool[c] = psum[c] * (1.0f / N_NODES) + fdec(pmax[c]);
}

// ---------------------------------------------------------------- late stage
__global__ void build_xlate(const float* __restrict__ cfg, const float* __restrict__ cmean,
                            const float* __restrict__ cstd, const float* __restrict__ pool,
                            short* __restrict__ xlateb)
{
  int i = blockIdx.x * blockDim.x + threadIdx.x;
  if (i >= N_CFG * K288) return;
  int r = i / K288, c = i % K288;
  float v;
  if (c < CFG_FEAT) v = (cfg[r * CFG_FEAT + c] - cmean[c]) / (cstd[c] + 1e-4f);
  else if (c < CFG_FEAT + HID) v = pool[c - CFG_FEAT];
  else v = 0.f;
  xlateb[i] = f2bf(v);
}

__global__ __launch_bounds__(64) void pred_kernel(
    const float* __restrict__ h2, const float* __restrict__ W,
    const float* __restrict__ b, float* __restrict__ out)
{
  int r = blockIdx.x, lane = threadIdx.x;
  float v = h2[(size_t)r * 128 + lane] * W[lane] +
            h2[(size_t)r * 128 + 64 + lane] * W[64 + lane];
  #pragma unroll
  for (int off = 32; off; off >>= 1) v += __shfl_xor(v, off);
  if (lane == 0) out[r] = v + b[0];
}

// ================================================================ launch
extern "C" void kernel_launch(void* const* d_in, const int* in_sizes, int n_in,
                              void* d_out, int out_size, void* d_ws, size_t ws_size,
                              hipStream_t stream)
{
  const float* node_feat   = (const float*)d_in[0];
  const float* config_feat = (const float*)d_in[1];
  const float* nf_mean     = (const float*)d_in[2];
  const float* nf_std      = (const float*)d_in[3];
  const float* cf_mean     = (const float*)d_in[4];
  const float* cf_std      = (const float*)d_in[5];
  const float* emb_table   = (const float*)d_in[6];
  const float* early_W1    = (const float*)d_in[7];
  const float* early_W2    = (const float*)d_in[8];
  const float* gat_Wl      = (const float*)d_in[9];
  const float* gat_bl      = (const float*)d_in[10];
  const float* gat_Wr      = (const float*)d_in[11];
  const float* gat_br      = (const float*)d_in[12];
  const float* gat_att     = (const float*)d_in[13];
  const float* gat_bias    = (const float*)d_in[14];
  const float* late_W1     = (const float*)d_in[15];
  const float* late_W2     = (const float*)d_in[16];
  const float* pred_W      = (const float*)d_in[17];
  const float* pred_b      = (const float*)d_in[18];
  const int*   node_opcode = (const int*)d_in[19];
  const int*   edge_index  = (const int*)d_in[20];
  float* out = (float*)d_out;
  (void)in_sizes; (void)n_in; (void)out_size; (void)ws_size;

  char* ws = (char*)d_ws;
  size_t off = 0;
  auto alloc = [&](size_t bytes) -> void* {
    void* p = ws + off;
    off += (bytes + 255) & ~255ull;
    return p;
  };
  short* x268b = (short*)alloc((size_t)MPAD * K288 * 2);
  float* bufB  = (float*)alloc((size_t)N_NODES * HID * 4);
  short* bufAb = (short*)alloc((size_t)MPAD * HID * 2);
  float* xlr   = (float*)alloc((size_t)N_NODES * NW * 4);
  float* stats = (float*)alloc(2 * HID * 4);
  int* counts  = (int*)alloc(N_NODES * 4);
  int* indptr  = (int*)alloc((N_NODES + 1) * 4);
  int* colidx  = (int*)alloc((size_t)E_TOT * 4);
  float* psum  = (float*)alloc(HID * 4);
  unsigned* pmax = (unsigned*)alloc(HID * 4);
  float* pool  = (float*)alloc(HID * 4);
  short* xlateb = (short*)alloc((size_t)1024 * K288 * 2);
  float* h1    = (float*)alloc((size_t)N_CFG * HID * 4);
  short* h1b   = (short*)alloc((size_t)1024 * HID * 2);
  float* h2    = (float*)alloc((size_t)N_CFG * 128 * 4);
  float* h2n   = (float*)alloc((size_t)N_CFG * 128 * 4);
  short* W1t   = (short*)alloc((size_t)HID * K288 * 2);
  short* W2t   = (short*)alloc((size_t)HID * HID * 2);
  short* Wlrt  = (short*)alloc((size_t)4 * NW * HID * 2);
  float* blr   = (float*)alloc(4 * NW * 4);
  short* lW1t  = (short*)alloc((size_t)HID * K288 * 2);
  short* lW2t  = (short*)alloc((size_t)128 * HID * 2);

  auto run_gemm = [&](const short* A, const short* Wt, const float* bias, float* C,
                      int M, int N, int Kpad) {
    dim3 grid((M + 127) / 128, N / 128);
    hipLaunchKernelGGL(gemm_mfma, grid, dim3(256), 0, stream, A, Wt, bias, C, M, N, Kpad);
  };
  auto run_norm = [&](const float* X, float* Yf, short* Yb, int M, int C) {
    hipMemsetAsync(stats, 0, 2 * C * sizeof(float), stream);
    hipLaunchKernelGGL(colstats, dim3((M + 63) / 64), dim3(C), 0, stream, X, M, C, stats);
    hipLaunchKernelGGL(norm_gelu, dim3((M * C + 255) / 256), dim3(256), 0, stream,
                       X, Yf, Yb, M, C, stats);
  };

  // weight prep (bf16 transposed)
  hipLaunchKernelGGL(convert_wt, dim3((HID * K288 + 255) / 256), dim3(256), 0, stream,
                     early_W1, W1t, EMB + OP_FEAT, HID, K288);
  hipLaunchKernelGGL(convert_wt, dim3((HID * HID + 255) / 256), dim3(256), 0, stream,
                     early_W2, W2t, HID, HID, HID);
  hipLaunchKernelGGL(convert_wt, dim3((HID * K288 + 255) / 256), dim3(256), 0, stream,
                     late_W1, lW1t, CFG_FEAT + HID, HID, K288);
  hipLaunchKernelGGL(convert_wt, dim3((128 * HID + 255) / 256), dim3(256), 0, stream,
                     late_W2, lW2t, HID, 128, HID);
  hipLaunchKernelGGL(gat_wt_prep, dim3((4 * NW * HID + 255) / 256), dim3(256), 0, stream,
                     gat_Wl, gat_Wr, Wlrt);
  hipLaunchKernelGGL(bias_cat, dim3((4 * NW + 255) / 256), dim3(256), 0, stream,
                     gat_bl, gat_br, blr);

  // CSR build
  hipMemsetAsync(counts, 0, N_NODES * 4, stream);
  hipLaunchKernelGGL(edge_count, dim3((E_TOT + 255) / 256), dim3(256), 0, stream,
                     edge_index, counts);
  hipLaunchKernelGGL(scan_kernel, dim3(1), dim3(1024), 0, stream, counts, indptr);
  hipMemsetAsync(counts, 0, N_NODES * 4, stream);
  hipLaunchKernelGGL(edge_fill, dim3((E_TOT + 255) / 256), dim3(256), 0, stream,
                     edge_index, indptr, counts, colidx);

  // prep + early MLP
  hipLaunchKernelGGL(prep_kernel, dim3((N_NODES + 3) / 4), dim3(256), 0, stream,
                     node_feat, nf_mean, nf_std, emb_table, node_opcode, x268b);
  run_gemm(x268b, W1t, nullptr, bufB, N_NODES, HID, K288);
  run_norm(bufB, nullptr, bufAb, N_NODES, HID);
  run_gemm(bufAb, W2t, nullptr, bufB, N_NODES, HID, HID);
  run_norm(bufB, nullptr, bufAb, N_NODES, HID);

  // 4 GAT layers
  for (int l = 0; l < 4; l++) {
    run_gemm(bufAb, Wlrt + (size_t)l * NW * HID, blr + l * NW, xlr, N_NODES, NW, HID);
    hipLaunchKernelGGL(gat_agg, dim3((N_NODES + 3) / 4), dim3(256), 0, stream,
                       xlr, indptr, colidx, gat_att + l * HID, gat_bias + l * HID, bufB);
    run_norm(bufB, nullptr, bufAb, N_NODES, HID);
  }

  // pooling
  hipMemsetAsync(psum, 0, HID * 4, stream);
  hipMemsetAsync(pmax, 0, HID * 4, stream);
  hipLaunchKernelGGL(pool_reduce, dim3((N_NODES + 63) / 64), dim3(HID), 0, stream,
                     bufAb, psum, pmax);
  hipLaunchKernelGGL(pool_finalize, dim3(1), dim3(HID), 0, stream, psum, pmax, pool);

  // late MLP
  hipLaunchKernelGGL(build_xlate, dim3((N_CFG * K288 + 255) / 256), dim3(256), 0, stream,
                     config_feat, cf_mean, cf_std, pool, xlateb);
  run_gemm(xlateb, lW1t, nullptr, h1, N_CFG, HID, K288);
  run_norm(h1, nullptr, h1b, N_CFG, HID);
  run_gemm(h1b, lW2t, nullptr, h2, N_CFG, 128, HID);
  run_norm(h2, h2n, nullptr, N_CFG, 128);
  hipLaunchKernelGGL(pred_kernel, dim3(N_CFG), dim3(64), 0, stream, h2n, pred_W, pred_b, out);
}

// Round 4
// 601.064 us; speedup vs baseline: 1.9434x; 1.1223x over previous
//
#include <hip/hip_runtime.h>
#include <math.h>

#define N_NODES 20000
#define N_EDGES 160000
#define N_CFG   1000
#define OP_FEAT 140
#define CFG_FEAT 24
#define HID     256
#define EMB     128
#define E_TOT   (N_EDGES + N_NODES)
#define K288    288          // 268 and 280 padded to multiple of 32
#define MPAD    20096        // 157 * 128
#define NW      512          // fused Wl|Wr output width

typedef __attribute__((ext_vector_type(8))) short short8v;
typedef __attribute__((ext_vector_type(4))) float f32x4;

__device__ __forceinline__ short f2bf(float f) {
  unsigned u = __float_as_uint(f);
  unsigned r = (u + 0x7FFFu + ((u >> 16) & 1u)) >> 16;
  return (short)r;
}
__device__ __forceinline__ float bf2f(short s) {
  return __uint_as_float(((unsigned)(unsigned short)s) << 16);
}
__device__ __forceinline__ float gelu_f(float x) {
  return 0.5f * x * (1.0f + erff(x * 0.70710678118654752f));
}

#define GLOAD_LDS(gptr, lptr) __builtin_amdgcn_global_load_lds( \
    (const __attribute__((address_space(1))) void*)(gptr),      \
    (__attribute__((address_space(3))) void*)(lptr), 16, 0, 0)

// ---------------------------------------------------------------- weight prep (merged)
__global__ void prep_weights(
    const float* __restrict__ eW1, const float* __restrict__ eW2,
    const float* __restrict__ lW1, const float* __restrict__ lW2,
    const float* __restrict__ Wl, const float* __restrict__ Wr,
    const float* __restrict__ bl, const float* __restrict__ br,
    short* __restrict__ W1t, short* __restrict__ W2t,
    short* __restrict__ lW1t, short* __restrict__ lW2t,
    short* __restrict__ Wlrt, float* __restrict__ blr)
{
  int i = blockIdx.x * 256 + threadIdx.x;
  const int s1 = HID * K288;      // W1t  [256][288]
  const int s2 = HID * HID;       // W2t  [256][256]
  const int s3 = HID * K288;      // lW1t [256][288]
  const int s4 = 128 * HID;       // lW2t [128][256]
  const int s5 = 4 * NW * HID;    // Wlrt [4][512][256]
  const int s6 = 4 * NW;          // blr
  if (i < s1) { int n = i / K288, k = i % K288;
    W1t[i] = (k < EMB + OP_FEAT) ? f2bf(eW1[(size_t)k * HID + n]) : (short)0; return; }
  i -= s1;
  if (i < s2) { int n = i >> 8, k = i & 255;
    W2t[i] = f2bf(eW2[(size_t)k * HID + n]); return; }
  i -= s2;
  if (i < s3) { int n = i / K288, k = i % K288;
    lW1t[i] = (k < CFG_FEAT + HID) ? f2bf(lW1[(size_t)k * HID + n]) : (short)0; return; }
  i -= s3;
  if (i < s4) { int n = i >> 8, k = i & 255;
    lW2t[i] = f2bf(lW2[(size_t)k * 128 + n]); return; }
  i -= s4;
  if (i < s5) { int l = i >> 17, rem = i & 131071, n = rem >> 8, k = rem & 255;
    float v = (n < HID) ? Wl[(size_t)l * HID * HID + (size_t)k * HID + n]
                        : Wr[(size_t)l * HID * HID + (size_t)k * HID + (n - HID)];
    Wlrt[i] = f2bf(v); return; }
  i -= s5;
  if (i < s6) { int l = i >> 9, j = i & 511;
    blr[i] = (j < HID) ? bl[l * HID + j] : br[l * HID + j - HID]; }
}

// ---------------------------------------------------------------- prep
__global__ __launch_bounds__(256) void prep_kernel(
    const float* __restrict__ node_feat, const float* __restrict__ nf_mean,
    const float* __restrict__ nf_std, const float* __restrict__ emb_table,
    const int* __restrict__ opcode, short* __restrict__ x268b)
{
  int wave = threadIdx.x >> 6;
  int lane = threadIdx.x & 63;
  int row = blockIdx.x * 4 + wave;
  if (row >= N_NODES) return;
  int op = opcode[row];
  float t0 = emb_table[op * EMB + lane];
  float t1 = emb_table[op * EMB + 64 + lane];
  float ss = t0 * t0 + t1 * t1;
  #pragma unroll
  for (int off = 32; off; off >>= 1) ss += __shfl_xor(ss, off);
  float sc = fminf(1.0f, 1.0f / (sqrtf(ss) + 1e-7f));
  short* dst = x268b + (size_t)row * K288;
  dst[lane] = f2bf(t0 * sc);
  dst[64 + lane] = f2bf(t1 * sc);
  for (int k = lane; k < OP_FEAT; k += 64)
    dst[EMB + k] = f2bf((node_feat[(size_t)row * OP_FEAT + k] - nf_mean[k]) / (nf_std[k] + 1e-4f));
  if (lane < K288 - EMB - OP_FEAT) dst[EMB + OP_FEAT + lane] = 0;
}

// ---------------------------------------------------------------- MFMA GEMM
// C[M,N] = A[M,Kpad]_bf16 @ Wt[N,Kpad]_bf16^T (+bias).
// If stats != nullptr, also accumulates per-column sum / sumsq (masked to gr<M).
__global__ __launch_bounds__(256) void gemm_mfma(
    const short* __restrict__ A, const short* __restrict__ Wt,
    const float* __restrict__ bias, float* __restrict__ C,
    float* __restrict__ stats, int M, int N, int Kpad)
{
  __shared__ __align__(16) short As[4][128][8];
  __shared__ __align__(16) short Bs[4][128][8];
  int tid = threadIdx.x;
  int wave = tid >> 6, lane = tid & 63;
  int bm = blockIdx.x * 128, bn = blockIdx.y * 128;
  int wr = (wave >> 1) * 64, wc = (wave & 1) * 64;
  int g = lane >> 4, r16 = lane & 15;
  f32x4 acc[4][4] = {};

  for (int k0 = 0; k0 < Kpad; k0 += 32) {
    #pragma unroll
    for (int s2 = 0; s2 < 2; s2++) {
      int s = wave * 2 + s2;
      int sg = s >> 1, r0 = (s & 1) * 64;
      GLOAD_LDS(A  + (size_t)(bm + r0 + lane) * Kpad + k0 + sg * 8, &As[sg][r0][0]);
      GLOAD_LDS(Wt + (size_t)(bn + r0 + lane) * Kpad + k0 + sg * 8, &Bs[sg][r0][0]);
    }
    __syncthreads();
    short8v af[4], bfv[4];
    #pragma unroll
    for (int mi = 0; mi < 4; mi++)
      af[mi] = *(const short8v*)&As[g][wr + mi * 16 + r16][0];
    #pragma unroll
    for (int ni = 0; ni < 4; ni++)
      bfv[ni] = *(const short8v*)&Bs[g][wc + ni * 16 + r16][0];
    #pragma unroll
    for (int mi = 0; mi < 4; mi++)
      #pragma unroll
      for (int ni = 0; ni < 4; ni++)
        acc[mi][ni] = __builtin_amdgcn_mfma_f32_16x16x32_bf16(af[mi], bfv[ni], acc[mi][ni], 0, 0, 0);
    __syncthreads();
  }

  int rg = lane >> 4;
  #pragma unroll
  for (int ni = 0; ni < 4; ni++) {
    int gc = bn + wc + ni * 16 + r16;
    float bv = bias ? bias[gc] : 0.f;
    float s = 0.f, sq = 0.f;
    #pragma unroll
    for (int mi = 0; mi < 4; mi++) {
      #pragma unroll
      for (int r = 0; r < 4; r++) {
        int gr = bm + wr + mi * 16 + rg * 4 + r;
        if (gr < M) {
          float v = acc[mi][ni][r] + bv;
          C[(size_t)gr * N + gc] = v;
          s += v; sq += v * v;
        }
      }
    }
    if (stats) {
      s  += __shfl_xor(s, 16);  sq += __shfl_xor(sq, 16);
      s  += __shfl_xor(s, 32);  sq += __shfl_xor(sq, 32);
      if (rg == 0) { atomicAdd(&stats[gc], s); atomicAdd(&stats[N + gc], sq); }
    }
  }
}

// ---------------------------------------------------------------- column stats (agg outputs)
__global__ void colstats(const float* __restrict__ X, int M, int C,
                         float* __restrict__ stats)
{
  int c = threadIdx.x;
  int r0 = blockIdx.x * 64;
  int r1 = min(r0 + 64, M);
  float s = 0.f, sq = 0.f;
  for (int r = r0; r < r1; r++) {
    float v = X[(size_t)r * C + c];
    s += v; sq += v * v;
  }
  atomicAdd(&stats[c], s);
  atomicAdd(&stats[C + c], sq);
}

// norm over rows + exact gelu; bf16 output
__global__ void norm_gelu(const float* __restrict__ X, short* __restrict__ Yb,
                          int M, int C, const float* __restrict__ stats)
{
  int i = blockIdx.x * blockDim.x + threadIdx.x;
  if (i >= M * C) return;
  int c = i % C;
  float invM = 1.0f / (float)M;
  float mean = stats[c] * invM;
  float var = stats[C + c] * invM - mean * mean;
  float y = gelu_f((X[i] - mean) * rsqrtf(var + 1e-5f));
  Yb[i] = f2bf(y);
}

// ---------------------------------------------------------------- CSR build
__global__ void edge_count(const int* __restrict__ ei, int* __restrict__ counts) {
  int e = blockIdx.x * blockDim.x + threadIdx.x;
  if (e >= E_TOT) return;
  int dst = (e < N_EDGES) ? ei[N_EDGES + e] : (e - N_EDGES);
  atomicAdd(&counts[dst], 1);
}

__global__ __launch_bounds__(1024) void scan_kernel(const int* __restrict__ counts,
                                                    int* __restrict__ indptr)
{
  __shared__ int sh[1024];
  int t = threadIdx.x;
  const int chunk = (N_NODES + 1023) / 1024;
  int start = t * chunk, end = min(start + chunk, N_NODES);
  int sum = 0;
  for (int i = start; i < end; i++) sum += counts[i];
  sh[t] = sum;
  __syncthreads();
  for (int off = 1; off < 1024; off <<= 1) {
    int v = (t >= off) ? sh[t - off] : 0;
    __syncthreads();
    sh[t] += v;
    __syncthreads();
  }
  int run = (t > 0) ? sh[t - 1] : 0;
  for (int i = start; i < end; i++) { indptr[i] = run; run += counts[i]; }
  if (t == 1023) indptr[N_NODES] = run;
}

__global__ void edge_fill(const int* __restrict__ ei, const int* __restrict__ indptr,
                          int* __restrict__ cursor, int* __restrict__ col)
{
  int e = blockIdx.x * blockDim.x + threadIdx.x;
  if (e >= E_TOT) return;
  int src, dst;
  if (e < N_EDGES) { src = ei[e]; dst = ei[N_EDGES + e]; }
  else             { src = dst = e - N_EDGES; }
  int pos = indptr[dst] + atomicAdd(&cursor[dst], 1);
  col[pos] = src;
}

// ---------------------------------------------------------------- GAT aggregation
__global__ __launch_bounds__(256) void gat_agg(
    const float* __restrict__ xlr,
    const int* __restrict__ indptr, const int* __restrict__ col,
    const float* __restrict__ att, const float* __restrict__ bias,
    float* __restrict__ out)
{
  int wave = threadIdx.x >> 6, lane = threadIdx.x & 63;
  int node = blockIdx.x * 4 + wave;
  if (node >= N_NODES) return;
  float attc[4], xri[4], o[4] = {0, 0, 0, 0};
  #pragma unroll
  for (int k = 0; k < 4; k++) {
    attc[k] = att[lane + 64 * k];
    xri[k] = xlr[(size_t)node * NW + HID + lane + 64 * k];
  }
  float m = -INFINITY, s = 0.f;
  int e0 = indptr[node], e1 = indptr[node + 1];
  for (int e = e0; e < e1; e++) {
    int j = col[e];
    float xlj[4], p = 0.f;
    #pragma unroll
    for (int k = 0; k < 4; k++) {
      xlj[k] = xlr[(size_t)j * NW + lane + 64 * k];
      float h = xlj[k] + xri[k];
      float lr = h > 0.f ? h : 0.2f * h;
      p += lr * attc[k];
    }
    #pragma unroll
    for (int off = 32; off; off >>= 1) p += __shfl_xor(p, off);
    float mn = fmaxf(m, p);
    float scale = __expf(m - mn);
    float w = __expf(p - mn);
    s = s * scale + w;
    #pragma unroll
    for (int k = 0; k < 4; k++) o[k] = o[k] * scale + w * xlj[k];
    m = mn;
  }
  float inv = 1.0f / (s + 1e-16f);
  #pragma unroll
  for (int k = 0; k < 4; k++)
    out[(size_t)node * HID + lane + 64 * k] = o[k] * inv + bias[lane + 64 * k];
}

// ---------------------------------------------------------------- pooling
__device__ __forceinline__ unsigned fenc(float f) {
  unsigned b = __float_as_uint(f);
  return (b & 0x80000000u) ? ~b : (b | 0x80000000u);
}
__device__ __forceinline__ float fdec(unsigned u) {
  unsigned b = (u & 0x80000000u) ? (u & 0x7FFFFFFFu) : ~u;
  return __uint_as_float(b);
}

__global__ void pool_reduce(const short* __restrict__ Xb, float* __restrict__ psum,
                            unsigned* __restrict__ pmax)
{
  int c = threadIdx.x;
  int r0 = blockIdx.x * 64, r1 = min(r0 + 64, N_NODES);
  float s = 0.f, mx = -INFINITY;
  for (int r = r0; r < r1; r++) {
    float v = bf2f(Xb[(size_t)r * HID + c]);
    s += v; mx = fmaxf(mx, v);
  }
  atomicAdd(&psum[c], s);
  atomicMax(&pmax[c], fenc(mx));
}

// ---------------------------------------------------------------- late stage
// builds xlate rows; pool value computed inline from psum/pmax
__global__ void build_xlate(const float* __restrict__ cfg, const float* __restrict__ cmean,
                            const float* __restrict__ cstd, const float* __restrict__ psum,
                            const unsigned* __restrict__ pmax, short* __restrict__ xlateb)
{
  int i = blockIdx.x * blockDim.x + threadIdx.x;
  if (i >= N_CFG * K288) return;
  int r = i / K288, c = i % K288;
  float v;
  if (c < CFG_FEAT) v = (cfg[r * CFG_FEAT + c] - cmean[c]) / (cstd[c] + 1e-4f);
  else if (c < CFG_FEAT + HID) {
    int p = c - CFG_FEAT;
    v = psum[p] * (1.0f / N_NODES) + fdec(pmax[p]);
  } else v = 0.f;
  xlateb[i] = f2bf(v);
}

// pred with fused final norm+gelu (stats from L2 GEMM epilogue)
__global__ __launch_bounds__(64) void pred_kernel(
    const float* __restrict__ h2, const float* __restrict__ stats,
    const float* __restrict__ W, const float* __restrict__ b,
    float* __restrict__ out)
{
  int r = blockIdx.x, lane = threadIdx.x;
  const float invM = 1.0f / (float)N_CFG;
  float v = 0.f;
  #pragma unroll
  for (int t = 0; t < 2; t++) {
    int c = lane + 64 * t;
    float mean = stats[c] * invM;
    float var = stats[128 + c] * invM - mean * mean;
    float y = gelu_f((h2[(size_t)r * 128 + c] - mean) * rsqrtf(var + 1e-5f));
    v += y * W[c];
  }
  #pragma unroll
  for (int off = 32; off; off >>= 1) v += __shfl_xor(v, off);
  if (lane == 0) out[r] = v + b[0];
}

// ================================================================ launch
extern "C" void kernel_launch(void* const* d_in, const int* in_sizes, int n_in,
                              void* d_out, int out_size, void* d_ws, size_t ws_size,
                              hipStream_t stream)
{
  const float* node_feat   = (const float*)d_in[0];
  const float* config_feat = (const float*)d_in[1];
  const float* nf_mean     = (const float*)d_in[2];
  const float* nf_std      = (const float*)d_in[3];
  const float* cf_mean     = (const float*)d_in[4];
  const float* cf_std      = (const float*)d_in[5];
  const float* emb_table   = (const float*)d_in[6];
  const float* early_W1    = (const float*)d_in[7];
  const float* early_W2    = (const float*)d_in[8];
  const float* gat_Wl      = (const float*)d_in[9];
  const float* gat_bl      = (const float*)d_in[10];
  const float* gat_Wr      = (const float*)d_in[11];
  const float* gat_br      = (const float*)d_in[12];
  const float* gat_att     = (const float*)d_in[13];
  const float* gat_bias    = (const float*)d_in[14];
  const float* late_W1     = (const float*)d_in[15];
  const float* late_W2     = (const float*)d_in[16];
  const float* pred_W      = (const float*)d_in[17];
  const float* pred_b      = (const float*)d_in[18];
  const int*   node_opcode = (const int*)d_in[19];
  const int*   edge_index  = (const int*)d_in[20];
  float* out = (float*)d_out;
  (void)in_sizes; (void)n_in; (void)out_size; (void)ws_size;

  char* ws = (char*)d_ws;
  size_t off = 0;
  auto alloc = [&](size_t bytes) -> void* {
    void* p = ws + off;
    off += (bytes + 255) & ~255ull;
    return p;
  };
  short* x268b = (short*)alloc((size_t)MPAD * K288 * 2);
  float* bufB  = (float*)alloc((size_t)N_NODES * HID * 4);
  short* bufAb = (short*)alloc((size_t)MPAD * HID * 2);
  float* xlr   = (float*)alloc((size_t)N_NODES * NW * 4);
  int* indptr  = (int*)alloc((N_NODES + 1) * 4);
  int* colidx  = (int*)alloc((size_t)E_TOT * 4);
  short* xlateb = (short*)alloc((size_t)1024 * K288 * 2);
  float* h1    = (float*)alloc((size_t)N_CFG * HID * 4);
  short* h1b   = (short*)alloc((size_t)1024 * HID * 2);
  float* h2    = (float*)alloc((size_t)N_CFG * 128 * 4);
  short* W1t   = (short*)alloc((size_t)HID * K288 * 2);
  short* W2t   = (short*)alloc((size_t)HID * HID * 2);
  short* Wlrt  = (short*)alloc((size_t)4 * NW * HID * 2);
  float* blr   = (float*)alloc(4 * NW * 4);
  short* lW1t  = (short*)alloc((size_t)HID * K288 * 2);
  short* lW2t  = (short*)alloc((size_t)128 * HID * 2);

  // ---- contiguous zero region (single memset per call) ----
  // 8 stats slots x 1024 f32 | psum 256 | pmax 256 | counts 20000 | cursor 20000
  float* zbase = (float*)alloc((8 * 1024 + 512 + 2 * N_NODES) * 4);
  float* stats8 = zbase;
  float* psum   = zbase + 8192;
  unsigned* pmax = (unsigned*)(zbase + 8192 + 256);
  int* counts   = (int*)(zbase + 8192 + 512);
  int* cursor   = counts + N_NODES;
  const size_t zbytes = (8 * 1024 + 512 + 2 * N_NODES) * 4;
  auto slot = [&](int s) { return stats8 + s * 1024; };
  // slots: 0=E1 1=E2 2..5=G0..G3 6=L1 7=L2

  auto run_gemm = [&](const short* A, const short* Wt, const float* bias, float* C,
                      float* stats, int M, int N, int Kpad) {
    dim3 grid((M + 127) / 128, N / 128);
    hipLaunchKernelGGL(gemm_mfma, grid, dim3(256), 0, stream, A, Wt, bias, C, stats, M, N, Kpad);
  };

  hipMemsetAsync(zbase, 0, zbytes, stream);

  // weight prep (one kernel)
  {
    int total = HID * K288 + HID * HID + HID * K288 + 128 * HID + 4 * NW * HID + 4 * NW;
    hipLaunchKernelGGL(prep_weights, dim3((total + 255) / 256), dim3(256), 0, stream,
                       early_W1, early_W2, late_W1, late_W2, gat_Wl, gat_Wr, gat_bl, gat_br,
                       W1t, W2t, lW1t, lW2t, Wlrt, blr);
  }

  // CSR build
  hipLaunchKernelGGL(edge_count, dim3((E_TOT + 255) / 256), dim3(256), 0, stream,
                     edge_index, counts);
  hipLaunchKernelGGL(scan_kernel, dim3(1), dim3(1024), 0, stream, counts, indptr);
  hipLaunchKernelGGL(edge_fill, dim3((E_TOT + 255) / 256), dim3(256), 0, stream,
                     edge_index, indptr, cursor, colidx);

  // prep + early MLP
  hipLaunchKernelGGL(prep_kernel, dim3((N_NODES + 3) / 4), dim3(256), 0, stream,
                     node_feat, nf_mean, nf_std, emb_table, node_opcode, x268b);
  run_gemm(x268b, W1t, nullptr, bufB, slot(0), N_NODES, HID, K288);
  hipLaunchKernelGGL(norm_gelu, dim3((N_NODES * HID + 255) / 256), dim3(256), 0, stream,
                     bufB, bufAb, N_NODES, HID, slot(0));
  run_gemm(bufAb, W2t, nullptr, bufB, slot(1), N_NODES, HID, HID);
  hipLaunchKernelGGL(norm_gelu, dim3((N_NODES * HID + 255) / 256), dim3(256), 0, stream,
                     bufB, bufAb, N_NODES, HID, slot(1));

  // 4 GAT layers
  for (int l = 0; l < 4; l++) {
    run_gemm(bufAb, Wlrt + (size_t)l * NW * HID, blr + l * NW, xlr, nullptr, N_NODES, NW, HID);
    hipLaunchKernelGGL(gat_agg, dim3((N_NODES + 3) / 4), dim3(256), 0, stream,
                       xlr, indptr, colidx, gat_att + l * HID, gat_bias + l * HID, bufB);
    hipLaunchKernelGGL(colstats, dim3((N_NODES + 63) / 64), dim3(HID), 0, stream,
                       bufB, N_NODES, HID, slot(2 + l));
    hipLaunchKernelGGL(norm_gelu, dim3((N_NODES * HID + 255) / 256), dim3(256), 0, stream,
                       bufB, bufAb, N_NODES, HID, slot(2 + l));
  }

  // pooling
  hipLaunchKernelGGL(pool_reduce, dim3((N_NODES + 63) / 64), dim3(HID), 0, stream,
                     bufAb, psum, pmax);

  // late MLP
  hipLaunchKernelGGL(build_xlate, dim3((N_CFG * K288 + 255) / 256), dim3(256), 0, stream,
                     config_feat, cf_mean, cf_std, psum, pmax, xlateb);
  run_gemm(xlateb, lW1t, nullptr, h1, slot(6), N_CFG, HID, K288);
  hipLaunchKernelGGL(norm_gelu, dim3((N_CFG * HID + 255) / 256), dim3(256), 0, stream,
                     h1, h1b, N_CFG, HID, slot(6));
  run_gemm(h1b, lW2t, nullptr, h2, slot(7), N_CFG, 128, HID);
  hipLaunchKernelGGL(pred_kernel, dim3(N_CFG), dim3(64), 0, stream,
                     h2, slot(7), pred_W, pred_b, out);
}